// Round 1
// baseline (3764.278 us; speedup 1.0000x reference)
//
#include <hip/hip_runtime.h>
#include <hip/hip_bf16.h>

// Problem constants (from setup_inputs)
constexpr int B    = 4096;
constexpr int T    = 80;
constexpr int CTXN = 10;    // CTX
constexpr int D    = 300;
constexpr int R    = 200;
constexpr int HA   = 100;
constexpr int TD   = 256;
constexpr int NTOK = 250;
constexpr int NTY  = 113;
constexpr int PL   = 3;
constexpr int G4   = 800;   // 4R
constexpr int KC   = 500;   // D + R (concat GEMM depth)
constexpr int CTX2 = 20;    // 2*CTX
constexpr int R2   = 400;   // 2R
constexpr int FEAT = 700;   // D + 2R

// GEMM tiling
constexpr int BM = 64;
constexpr int BN = 64;
constexpr int BK = 16;

// ---------------------------------------------------------------------------
// f1 = mean of mention word vectors -> feat[:, 0:300]
__global__ void k_f1(const int* __restrict__ ment_idx,
                     const float* __restrict__ ment_lent,
                     const int* __restrict__ input_data,
                     const float* __restrict__ we,
                     float* __restrict__ feat) {
    int b = blockIdx.x;
    __shared__ int wrow[5];
    if (threadIdx.x < 5) {
        int idx = ment_idx[b * 5 + threadIdx.x];
        wrow[threadIdx.x] = (idx >= 0 && idx < B * T) ? input_data[idx] : -1;
    }
    __syncthreads();
    float inv = 1.0f / ment_lent[b];
    for (int d = threadIdx.x; d < D; d += blockDim.x) {
        float s = 0.f;
        #pragma unroll
        for (int j = 0; j < 5; ++j) {
            int w = wrow[j];
            if (w >= 0) s += we[(size_t)w * D + d];
        }
        feat[(size_t)b * FEAT + d] = s * inv;
    }
}

// ---------------------------------------------------------------------------
// gather context word vectors: xL, xR [B*CTX, D]
__global__ void k_gather(const int* __restrict__ idxL,
                         const int* __restrict__ idxR,
                         const int* __restrict__ input_data,
                         const float* __restrict__ we,
                         float* __restrict__ xL, float* __restrict__ xR) {
    int bid = blockIdx.x;            // [0, 2*B*CTX)
    int side = bid / (B * CTXN);
    int bt   = bid % (B * CTXN);
    const int* idxA = side ? idxR : idxL;
    float* xdst = side ? xR : xL;
    int idx = idxA[bt];
    int w = (idx >= 0 && idx < B * T) ? input_data[idx] : -1;
    float* dst = xdst + (size_t)bt * D;
    if (w >= 0) {
        const float* src = we + (size_t)w * D;
        for (int d = threadIdx.x; d < D; d += blockDim.x) dst[d] = src[d];
    } else {
        for (int d = threadIdx.x; d < D; d += blockDim.x) dst[d] = 0.f;
    }
}

// ---------------------------------------------------------------------------
// Generic tiled fp32 GEMM: C = act(A[M,K](lda) @ Bm[K,N](ldb) + bias)
__global__ __launch_bounds__(256) void k_gemm(
    const float* __restrict__ A, int lda,
    const float* __restrict__ Bm, int ldb,
    const float* __restrict__ bias,
    float* __restrict__ Cm, int ldc,
    int N, int K, int act) {
    __shared__ __align__(16) float As[BK][BM + 4];
    __shared__ __align__(16) float Bs[BK][BN + 4];
    int tid = threadIdx.x;
    int m0 = blockIdx.y * BM, n0 = blockIdx.x * BN;
    int tx = tid & 15, ty = tid >> 4;
    float acc[4][4] = {};
    for (int k0 = 0; k0 < K; k0 += BK) {
        for (int l = tid; l < BM * BK; l += 256) {
            int r = l >> 4, kk = l & 15;
            int k = k0 + kk;
            As[kk][r] = (k < K) ? A[(size_t)(m0 + r) * lda + k] : 0.f;
        }
        for (int l = tid; l < BK * BN; l += 256) {
            int kk = l >> 6, j = l & 63;
            int k = k0 + kk, col = n0 + j;
            Bs[kk][j] = (k < K && col < N) ? Bm[(size_t)k * ldb + col] : 0.f;
        }
        __syncthreads();
        #pragma unroll
        for (int kk = 0; kk < BK; ++kk) {
            float4 av = *reinterpret_cast<const float4*>(&As[kk][ty * 4]);
            float4 bv = *reinterpret_cast<const float4*>(&Bs[kk][tx * 4]);
            float a[4] = {av.x, av.y, av.z, av.w};
            float bb[4] = {bv.x, bv.y, bv.z, bv.w};
            #pragma unroll
            for (int i = 0; i < 4; ++i)
                #pragma unroll
                for (int j = 0; j < 4; ++j) acc[i][j] += a[i] * bb[j];
        }
        __syncthreads();
    }
    #pragma unroll
    for (int i = 0; i < 4; ++i) {
        int m = m0 + ty * 4 + i;
        #pragma unroll
        for (int j = 0; j < 4; ++j) {
            int col = n0 + tx * 4 + j;
            if (col < N) {
                float v = acc[i][j] + (bias ? bias[col] : 0.f);
                if (act) v = fmaxf(v, 0.f);
                Cm[(size_t)m * ldc + col] = v;
            }
        }
    }
}

// ---------------------------------------------------------------------------
// LSTM gate GEMM: gates[inst][b][j] = sum_k [x_t | h]@[Wx;Wh], inst = z
// inst: 0=(L,f) 1=(L,b) 2=(R,f) 3=(R,b)
__global__ __launch_bounds__(256) void k_gates(
    const float* __restrict__ xL, const float* __restrict__ xR,
    const float* __restrict__ hbuf,
    const float* __restrict__ Wx_f, const float* __restrict__ Wh_f,
    const float* __restrict__ Wx_b, const float* __restrict__ Wh_b,
    const float* __restrict__ lentL, const float* __restrict__ lentR,
    float* __restrict__ gbuf, int s) {
    int inst = blockIdx.z;
    int side = inst >> 1, dir = inst & 1;
    const float* x  = side ? xR : xL;
    const float* Wx = dir ? Wx_b : Wx_f;
    const float* Wh = dir ? Wh_b : Wh_f;
    const float* lent = side ? lentR : lentL;
    const float* h = hbuf + (size_t)inst * B * R;
    float* g = gbuf + (size_t)inst * B * G4;

    __shared__ __align__(16) float As[BK][BM + 4];
    __shared__ __align__(16) float Bs[BK][BN + 4];
    __shared__ int xoff[BM];

    int tid = threadIdx.x;
    int m0 = blockIdx.y * BM, n0 = blockIdx.x * BN;
    int tx = tid & 15, ty = tid >> 4;

    if (tid < BM) {
        int b = m0 + tid;
        int len = (int)lent[b];
        int tt = dir ? ((s < len) ? (len - 1 - s) : s) : s;
        xoff[tid] = (b * CTXN + tt) * D;
    }
    __syncthreads();

    float acc[4][4] = {};
    for (int k0 = 0; k0 < KC; k0 += BK) {
        for (int l = tid; l < BM * BK; l += 256) {
            int r = l >> 4, kk = l & 15;
            int k = k0 + kk;
            float v;
            if (k < D)        v = x[xoff[r] + k];
            else if (k < KC)  v = h[(size_t)(m0 + r) * R + (k - D)];
            else              v = 0.f;
            As[kk][r] = v;
        }
        for (int l = tid; l < BK * BN; l += 256) {
            int kk = l >> 6, j = l & 63;
            int k = k0 + kk, col = n0 + j;
            float v = 0.f;
            if (col < G4) {
                if (k < D)       v = Wx[(size_t)k * G4 + col];
                else if (k < KC) v = Wh[(size_t)(k - D) * G4 + col];
            }
            Bs[kk][j] = v;
        }
        __syncthreads();
        #pragma unroll
        for (int kk = 0; kk < BK; ++kk) {
            float4 av = *reinterpret_cast<const float4*>(&As[kk][ty * 4]);
            float4 bv = *reinterpret_cast<const float4*>(&Bs[kk][tx * 4]);
            float a[4] = {av.x, av.y, av.z, av.w};
            float bb[4] = {bv.x, bv.y, bv.z, bv.w};
            #pragma unroll
            for (int i = 0; i < 4; ++i)
                #pragma unroll
                for (int j = 0; j < 4; ++j) acc[i][j] += a[i] * bb[j];
        }
        __syncthreads();
    }
    #pragma unroll
    for (int i = 0; i < 4; ++i) {
        int m = m0 + ty * 4 + i;
        #pragma unroll
        for (int j = 0; j < 4; ++j) {
            int col = n0 + tx * 4 + j;
            if (col < G4) g[(size_t)m * G4 + col] = acc[i][j];
        }
    }
}

// ---------------------------------------------------------------------------
// LSTM cell pointwise: gates -> h,c update + masked ctx write
__global__ void k_cell(const float* __restrict__ gbuf,
                       const float* __restrict__ b_f, const float* __restrict__ b_b,
                       const float* __restrict__ lentL, const float* __restrict__ lentR,
                       float* __restrict__ hbuf, float* __restrict__ cbuf,
                       float* __restrict__ ctx, int s) {
    int gid = blockIdx.x * blockDim.x + threadIdx.x;
    if (gid >= 4 * B * R) return;
    int r = gid % R;
    int b = (gid / R) % B;
    int inst = gid / (B * R);
    int side = inst >> 1, dir = inst & 1;
    const float* g = gbuf + ((size_t)inst * B + b) * G4;
    const float* bias = dir ? b_b : b_f;
    float gi = g[r]           + bias[r];
    float gf = g[R + r]       + bias[R + r];
    float gg = g[2 * R + r]   + bias[2 * R + r];
    float go = g[3 * R + r]   + bias[3 * R + r];
    size_t hoff = ((size_t)inst * B + b) * R + r;
    float c_old = cbuf[hoff];
    float si = 1.f / (1.f + expf(-gi));
    float sf = 1.f / (1.f + expf(-gf));
    float so = 1.f / (1.f + expf(-go));
    float c_new = sf * c_old + si * tanhf(gg);
    float h_new = so * tanhf(c_new);
    int len = (int)((side ? lentR : lentL)[b]);
    if (s < len) {
        hbuf[hoff] = h_new;
        cbuf[hoff] = c_new;
        int tpos = dir ? (len - 1 - s) : s;
        ctx[((size_t)b * CTX2 + side * CTXN + tpos) * R2 + dir * R + r] = h_new;
    }
}

// ---------------------------------------------------------------------------
// attention: per-batch-row block. att=relu(ctx@h1+fm); w=softmax(att@h2);
// feat[:,300:700] = sum_t w[t]*ctx[t]
__global__ __launch_bounds__(256) void k_attn(const float* __restrict__ ctx,
                                              const float* __restrict__ fm,
                                              const float* __restrict__ h1,
                                              const float* __restrict__ h2,
                                              float* __restrict__ feat) {
    int b = blockIdx.x;
    __shared__ float cs[CTX2][R2];
    __shared__ float att[CTX2][HA];
    __shared__ float sc[CTX2];
    const float* cb = ctx + (size_t)b * CTX2 * R2;
    for (int l = threadIdx.x; l < CTX2 * R2; l += 256) cs[l / R2][l % R2] = cb[l];
    __syncthreads();
    for (int l = threadIdx.x; l < CTX2 * HA; l += 256) {
        int t = l / HA, hh = l % HA;
        float acc = fm[(size_t)b * HA + hh];
        for (int r = 0; r < R2; ++r) acc += cs[t][r] * h1[(size_t)r * HA + hh];
        att[t][hh] = fmaxf(acc, 0.f);
    }
    __syncthreads();
    if (threadIdx.x < CTX2) {
        int t = threadIdx.x;
        float acc = 0.f;
        for (int hh = 0; hh < HA; ++hh) acc += att[t][hh] * h2[hh];
        sc[t] = acc;
    }
    __syncthreads();
    float mx = -1e30f;
    #pragma unroll
    for (int t = 0; t < CTX2; ++t) mx = fmaxf(mx, sc[t]);
    float w[CTX2];
    float sum = 0.f;
    #pragma unroll
    for (int t = 0; t < CTX2; ++t) { w[t] = expf(sc[t] - mx); sum += w[t]; }
    float inv = 1.f / sum;
    for (int rr = threadIdx.x; rr < R2; rr += 256) {
        float acc = 0.f;
        #pragma unroll
        for (int t = 0; t < CTX2; ++t) acc += w[t] * cs[t][rr];
        feat[(size_t)b * FEAT + D + rr] = acc * inv;
    }
}

// ---------------------------------------------------------------------------
__device__ __forceinline__ float blk_sum_256(float v, float* red) {
    #pragma unroll
    for (int o = 32; o > 0; o >>= 1) v += __shfl_down(v, o, 64);
    int lane = threadIdx.x & 63, wid = threadIdx.x >> 6;
    if (lane == 0) red[wid] = v;
    __syncthreads();
    float t = red[0] + red[1] + red[2] + red[3];
    __syncthreads();
    return t;
}

// l2-normalize rows in place (blockDim must be 256)
__global__ void k_l2norm(float* __restrict__ x, int ncol) {
    int row = blockIdx.x;
    float* p = x + (size_t)row * ncol;
    __shared__ float red[4];
    float ss = 0.f;
    for (int c = threadIdx.x; c < ncol; c += 256) { float v = p[c]; ss += v * v; }
    float tot = blk_sum_256(ss, red);
    float scale = 1.f / sqrtf(fmaxf(tot, 1e-12f));
    for (int c = threadIdx.x; c < ncol; c += 256) p[c] *= scale;
}

// type-path embeddings: sum PL token rows then l2norm (blockDim = 256 = TD)
__global__ void k_typenorm(const int* __restrict__ type_path,
                           const float* __restrict__ type_tok,
                           float* __restrict__ tnorm) {
    int y = blockIdx.x;
    int c = threadIdx.x;
    __shared__ float red[4];
    float s = 0.f;
    #pragma unroll
    for (int j = 0; j < PL; ++j) {
        int tk = type_path[y * PL + j];
        if (tk >= 0 && tk < NTOK) s += type_tok[(size_t)tk * TD + c];
    }
    float tot = blk_sum_256(s * s, red);
    float scale = 1.f / sqrtf(fmaxf(tot, 1e-12f));
    tnorm[(size_t)y * TD + c] = s * scale;
}

// final scoring: out[b,y] = dot(ent[b], tnorm[y])
__global__ void k_final(const float* __restrict__ ent,
                        const float* __restrict__ tnorm,
                        float* __restrict__ out) {
    int b = blockIdx.x;
    __shared__ float es[TD];
    for (int c = threadIdx.x; c < TD; c += blockDim.x) es[c] = ent[(size_t)b * TD + c];
    __syncthreads();
    for (int y = threadIdx.x; y < NTY; y += blockDim.x) {
        const float* tn = tnorm + (size_t)y * TD;
        float acc = 0.f;
        #pragma unroll 4
        for (int k = 0; k < TD; ++k) acc += es[k] * tn[k];
        out[(size_t)b * NTY + y] = acc;
    }
}

// ---------------------------------------------------------------------------
extern "C" void kernel_launch(void* const* d_in, const int* in_sizes, int n_in,
                              void* d_out, int out_size, void* d_ws, size_t ws_size,
                              hipStream_t stream) {
    const int*   input_data       = (const int*)d_in[0];
    const int*   entMentIndex     = (const int*)d_in[1];
    const int*   entCtxLeftIndex  = (const int*)d_in[2];
    const int*   entCtxRightIndex = (const int*)d_in[3];
    const float* entMentLent      = (const float*)d_in[4];
    const float* ctxLeftLent      = (const float*)d_in[5];
    const float* ctxRightLent     = (const float*)d_in[6];
    const int*   type_path        = (const int*)d_in[7];
    const float* word_embed       = (const float*)d_in[8];
    const float* h_m              = (const float*)d_in[9];
    const float* h1               = (const float*)d_in[10];
    const float* h2               = (const float*)d_in[11];
    const float* Wx_f             = (const float*)d_in[12];
    const float* Wh_f             = (const float*)d_in[13];
    const float* b_f              = (const float*)d_in[14];
    const float* Wx_b             = (const float*)d_in[15];
    const float* Wh_b             = (const float*)d_in[16];
    const float* b_b              = (const float*)d_in[17];
    const float* dense_W          = (const float*)d_in[18];
    const float* dense_b          = (const float*)d_in[19];
    const float* type_tok         = (const float*)d_in[20];
    float* out = (float*)d_out;

    float* ws = (float*)d_ws;
    float* feat  = ws; ws += (size_t)B * FEAT;        // [B,700]
    float* fm    = ws; ws += (size_t)B * HA;          // [B,100]
    float* xL    = ws; ws += (size_t)B * CTXN * D;    // [B*10,300]
    float* xR    = ws; ws += (size_t)B * CTXN * D;
    float* hbuf  = ws; ws += (size_t)4 * B * R;       // [4,B,200]
    float* cbuf  = ws; ws += (size_t)4 * B * R;
    float* gbuf  = ws; ws += (size_t)4 * B * G4;      // [4,B,800]
    float* ctx   = ws; ws += (size_t)B * CTX2 * R2;   // [B,20,400]
    float* ent   = ws; ws += (size_t)B * TD;          // [B,256]
    float* tnorm = ws; ws += (size_t)NTY * TD;        // [113,256]

    // zero-init recurrent state and ctx (reference masks to exact zeros)
    hipMemsetAsync(hbuf, 0, (size_t)8 * B * R * sizeof(float), stream);
    hipMemsetAsync(ctx, 0, (size_t)B * CTX2 * R2 * sizeof(float), stream);

    k_f1<<<B, 256, 0, stream>>>(entMentIndex, entMentLent, input_data, word_embed, feat);
    k_gather<<<2 * B * CTXN, 128, 0, stream>>>(entCtxLeftIndex, entCtxRightIndex,
                                               input_data, word_embed, xL, xR);
    // fm = f1 @ h_m
    {
        dim3 g((HA + BN - 1) / BN, B / BM);
        k_gemm<<<g, 256, 0, stream>>>(feat, FEAT, h_m, HA, nullptr, fm, HA, HA, D, 0);
    }
    // 10 recurrent steps, 4 LSTM instances each
    for (int s = 0; s < CTXN; ++s) {
        dim3 gg((G4 + BN - 1) / BN, B / BM, 4);
        k_gates<<<gg, 256, 0, stream>>>(xL, xR, hbuf, Wx_f, Wh_f, Wx_b, Wh_b,
                                        ctxLeftLent, ctxRightLent, gbuf, s);
        int nthr = 4 * B * R;
        k_cell<<<(nthr + 255) / 256, 256, 0, stream>>>(gbuf, b_f, b_b,
                                                       ctxLeftLent, ctxRightLent,
                                                       hbuf, cbuf, ctx, s);
    }
    k_attn<<<B, 256, 0, stream>>>(ctx, fm, h1, h2, feat);
    // ent = relu(feat @ dense_W + dense_b), then l2norm rows
    {
        dim3 g((TD + BN - 1) / BN, B / BM);
        k_gemm<<<g, 256, 0, stream>>>(feat, FEAT, dense_W, TD, dense_b, ent, TD, TD, FEAT, 1);
    }
    k_l2norm<<<B, 256, 0, stream>>>(ent, TD);
    k_typenorm<<<NTY, TD, 0, stream>>>(type_path, type_tok, tnorm);
    k_final<<<B, 128, 0, stream>>>(ent, tnorm, out);
}

// Round 2
// 791.042 us; speedup vs baseline: 4.7586x; 4.7586x over previous
//
#include <hip/hip_runtime.h>
#include <hip/hip_bf16.h>

// Problem constants
constexpr int B    = 4096;
constexpr int T    = 80;
constexpr int CTXN = 10;
constexpr int D    = 300;
constexpr int R    = 200;
constexpr int HA   = 100;
constexpr int TD   = 256;
constexpr int NTY  = 113;
constexpr int PL   = 3;
constexpr int NTOK = 250;
constexpr int CTX2 = 20;    // 2*CTX
constexpr int R2   = 400;   // 2R
constexpr int FEAT = 700;   // D + 2R

// padded layout constants
constexpr int XS   = 304;   // x row stride (300 + 4 pad), 16B-granule aligned
constexpr int KAH  = 512;   // gates GEMM K: [h 0..199 | x 200..503 | pad]
constexpr int G4P  = 832;   // padded 4R (800 -> 832 = 13*64)
constexpr int CTXS = 448;   // ctx row stride (400 -> 448 = 7*64)
constexpr int F1S  = 320;   // f1 row stride (300 -> 320)
constexpr int FBS  = 704;   // feat row stride (700 -> 704 = 11*64)
constexpr int FMS  = 128;   // fm / att col stride (100 -> 128)

typedef __attribute__((ext_vector_type(8))) short bf16x8;
typedef __attribute__((ext_vector_type(4))) float f32x4;

__device__ __forceinline__ ushort f2bf(float f) {
    union { float f; uint32_t u; } x{f};
    uint32_t r = x.u + 0x7fff + ((x.u >> 16) & 1);
    return (ushort)(r >> 16);
}
__device__ __forceinline__ float bf2f(ushort u) {
    union { uint32_t u; float f; } x{(uint32_t)u << 16};
    return x.f;
}

#define GLD_LDS(g, l) __builtin_amdgcn_global_load_lds( \
    (const __attribute__((address_space(1))) void*)(g), \
    (__attribute__((address_space(3))) void*)(l), 16, 0, 0)

// ---------------------------------------------------------------------------
// weight prep: Wt[dir][n 832][k 512] bf16, k = [Wh(200) | Wx(304) | 0]
__global__ void k_prepw(const float* __restrict__ Wx_f, const float* __restrict__ Wh_f,
                        const float* __restrict__ Wx_b, const float* __restrict__ Wh_b,
                        ushort* __restrict__ Wt) {
    int gid = blockIdx.x * blockDim.x + threadIdx.x;
    if (gid >= 2 * G4P * KAH) return;
    int k = gid & (KAH - 1);
    int q = gid / KAH;
    int n = q % G4P, dir = q / G4P;
    const float* Wx = dir ? Wx_b : Wx_f;
    const float* Wh = dir ? Wh_b : Wh_f;
    float v = 0.f;
    if (n < 800) {
        if (k < R)               v = Wh[(size_t)k * 800 + n];
        else if (k - R < D)      v = Wx[(size_t)(k - R) * 800 + n];
    }
    Wt[gid] = f2bf(v);
}

// h1t[n 128][k 448]
__global__ void k_preph1(const float* __restrict__ h1, ushort* __restrict__ h1t) {
    int gid = blockIdx.x * blockDim.x + threadIdx.x;
    if (gid >= FMS * CTXS) return;
    int k = gid % CTXS, n = gid / CTXS;
    float v = (n < HA && k < R2) ? h1[(size_t)k * HA + n] : 0.f;
    h1t[gid] = f2bf(v);
}
// h_mt[n 128][k 320]
__global__ void k_prephm(const float* __restrict__ h_m, ushort* __restrict__ h_mt) {
    int gid = blockIdx.x * blockDim.x + threadIdx.x;
    if (gid >= FMS * F1S) return;
    int k = gid % F1S, n = gid / F1S;
    float v = (n < HA && k < D) ? h_m[(size_t)k * HA + n] : 0.f;
    h_mt[gid] = f2bf(v);
}
// dWt[n 256][k 704]
__global__ void k_prepdw(const float* __restrict__ dW, ushort* __restrict__ dWt) {
    int gid = blockIdx.x * blockDim.x + threadIdx.x;
    if (gid >= TD * FBS) return;
    int k = gid % FBS, n = gid / FBS;
    float v = (k < FEAT) ? dW[(size_t)k * TD + n] : 0.f;
    dWt[gid] = f2bf(v);
}

// ---------------------------------------------------------------------------
// gather context word vectors -> bf16 rows stride 304, pad cols zeroed
__global__ void k_gatherb(const int* __restrict__ idxL, const int* __restrict__ idxR,
                          const int* __restrict__ input_data,
                          const float* __restrict__ we,
                          ushort* __restrict__ xLb, ushort* __restrict__ xRb) {
    int row = blockIdx.x * 4 + (threadIdx.x >> 6);
    int lane = threadIdx.x & 63;
    if (row >= 2 * B * CTXN) return;
    int side = row / (B * CTXN);
    int bt = row % (B * CTXN);
    int idx = (side ? idxR : idxL)[bt];
    int w = (idx >= 0 && idx < B * T) ? input_data[idx] : -1;
    ushort* dst = (side ? xRb : xLb) + (size_t)bt * XS;
    if (lane < XS / 8) {
        int e0 = lane * 8;
        ushort tmp[8];
        #pragma unroll
        for (int j = 0; j < 8; ++j) {
            int e = e0 + j;
            float f = (w >= 0 && e < D) ? we[(size_t)w * D + e] : 0.f;
            tmp[j] = f2bf(f);
        }
        *reinterpret_cast<bf16x8*>(dst + e0) = *reinterpret_cast<bf16x8*>(tmp);
    }
}

// ---------------------------------------------------------------------------
// f1 = mean of mention vectors -> featb[:,0:300] and f1b[:,0:300] (bf16)
__global__ void k_f1(const int* __restrict__ ment_idx,
                     const float* __restrict__ ment_lent,
                     const int* __restrict__ input_data,
                     const float* __restrict__ we,
                     ushort* __restrict__ featb, ushort* __restrict__ f1b) {
    int b = blockIdx.x;
    __shared__ int wrow[5];
    if (threadIdx.x < 5) {
        int idx = ment_idx[b * 5 + threadIdx.x];
        wrow[threadIdx.x] = (idx >= 0 && idx < B * T) ? input_data[idx] : -1;
    }
    __syncthreads();
    float inv = 1.0f / ment_lent[b];
    for (int d = threadIdx.x; d < D; d += blockDim.x) {
        float s = 0.f;
        #pragma unroll
        for (int j = 0; j < 5; ++j) {
            int w = wrow[j];
            if (w >= 0) s += we[(size_t)w * D + d];
        }
        ushort u = f2bf(s * inv);
        featb[(size_t)b * FBS + d] = u;
        f1b[(size_t)b * F1S + d] = u;
    }
}

// ---------------------------------------------------------------------------
// Generic MFMA GEMM: C[M x N] = epi(A[M x K]bf16 @ Bt[N x K]bf16^T)
// BM=128, BN=64, BK=64. M % 128 == 0, N % 64 == 0, K % 64 == 0.
// MODE 1: bias(aux)+relu -> fp32 C   (dense)
// MODE 2: += aux[(row/20)*128 + col], relu -> fp32 C   (att)
// MODE 3: plain fp32 C   (fm)
template<int MODE>
__global__ __launch_bounds__(256) void k_mfma(
    const ushort* __restrict__ A, int lda,
    const ushort* __restrict__ Bt, int ldb,
    float* __restrict__ C, int ldc, int K,
    const float* __restrict__ aux) {
    __shared__ __align__(16) ushort As[128 * 64];
    __shared__ __align__(16) ushort Bs[64 * 64];
    int tid = threadIdx.x, wave = tid >> 6, lane = tid & 63;
    int m0 = blockIdx.y * 128, n0 = blockIdx.x * 64;
    int wr = wave >> 1, wc = wave & 1;
    f32x4 acc[4][2] = {};

    for (int k0 = 0; k0 < K; k0 += 64) {
        #pragma unroll
        for (int p = 0; p < 4; ++p) {
            int chunk = p * 4 + wave;
            int row = chunk * 8 + (lane >> 3);
            int ss = (lane & 7) ^ (row & 7);
            const ushort* g = A + (size_t)(m0 + row) * lda + k0 + ss * 8;
            GLD_LDS(g, As + chunk * 512);
        }
        #pragma unroll
        for (int p = 0; p < 2; ++p) {
            int chunk = p * 4 + wave;
            int row = chunk * 8 + (lane >> 3);
            int ss = (lane & 7) ^ (row & 7);
            const ushort* g = Bt + (size_t)(n0 + row) * ldb + k0 + ss * 8;
            GLD_LDS(g, Bs + chunk * 512);
        }
        __syncthreads();
        #pragma unroll
        for (int kk = 0; kk < 2; ++kk) {
            bf16x8 a[4], bf[2];
            #pragma unroll
            for (int m = 0; m < 4; ++m) {
                int r = wr * 64 + m * 16 + (lane & 15);
                int ss = (kk * 4 + (lane >> 4)) ^ (r & 7);
                a[m] = *(const bf16x8*)&As[r * 64 + ss * 8];
            }
            #pragma unroll
            for (int n = 0; n < 2; ++n) {
                int r = wc * 32 + n * 16 + (lane & 15);
                int ss = (kk * 4 + (lane >> 4)) ^ (r & 7);
                bf[n] = *(const bf16x8*)&Bs[r * 64 + ss * 8];
            }
            #pragma unroll
            for (int m = 0; m < 4; ++m)
                #pragma unroll
                for (int n = 0; n < 2; ++n)
                    acc[m][n] = __builtin_amdgcn_mfma_f32_16x16x32_bf16(a[m], bf[n], acc[m][n], 0, 0, 0);
        }
        __syncthreads();
    }
    #pragma unroll
    for (int m = 0; m < 4; ++m) {
        #pragma unroll
        for (int n = 0; n < 2; ++n) {
            int c = n0 + wc * 32 + n * 16 + (lane & 15);
            #pragma unroll
            for (int j = 0; j < 4; ++j) {
                int rr = m0 + wr * 64 + m * 16 + (lane >> 4) * 4 + j;
                float v = acc[m][n][j];
                if (MODE == 1) v = fmaxf(v + aux[c], 0.f);
                if (MODE == 2) v = fmaxf(v + aux[(size_t)(rr / CTX2) * FMS + c], 0.f);
                C[(size_t)rr * ldc + c] = v;
            }
        }
    }
}

// ---------------------------------------------------------------------------
// LSTM gate GEMM (per step): gates = [h | x_t] @ Wt[dir]^T, bf16 out
__global__ __launch_bounds__(256) void k_gates_mfma(
    const ushort* __restrict__ xLb, const ushort* __restrict__ xRb,
    const ushort* __restrict__ hb, const ushort* __restrict__ Wt,
    const float* __restrict__ lentL, const float* __restrict__ lentR,
    const ushort* __restrict__ zbuf,
    ushort* __restrict__ gb, int s) {
    __shared__ __align__(16) ushort As[128 * 64];
    __shared__ __align__(16) ushort Bs[64 * 64];
    __shared__ int xoff[128];
    int tid = threadIdx.x, wave = tid >> 6, lane = tid & 63;
    int z = blockIdx.z, side = z >> 1, dir = z & 1;
    const ushort* xb = side ? xRb : xLb;
    const float* lent = side ? lentR : lentL;
    int m0 = blockIdx.y * 128, n0 = blockIdx.x * 64;
    const ushort* W = Wt + (size_t)dir * G4P * KAH;
    const ushort* hbase = hb + (size_t)z * B * R;

    if (tid < 128) {
        int b = m0 + tid;
        int len = (int)lent[b];
        int tt = dir ? ((s < len) ? (len - 1 - s) : s) : s;
        xoff[tid] = (b * CTXN + tt) * XS;
    }
    __syncthreads();

    int wr = wave >> 1, wc = wave & 1;
    f32x4 acc[4][2] = {};

    for (int k0 = 0; k0 < KAH; k0 += 64) {
        #pragma unroll
        for (int p = 0; p < 4; ++p) {
            int chunk = p * 4 + wave;
            int row = chunk * 8 + (lane >> 3);
            int ss = (lane & 7) ^ (row & 7);
            int k = k0 + ss * 8;
            const ushort* g;
            if (k < R)            g = hbase + (size_t)(m0 + row) * R + k;
            else if (k < R + XS)  g = xb + xoff[row] + (k - R);
            else                  g = zbuf;
            GLD_LDS(g, As + chunk * 512);
        }
        #pragma unroll
        for (int p = 0; p < 2; ++p) {
            int chunk = p * 4 + wave;
            int row = chunk * 8 + (lane >> 3);
            int ss = (lane & 7) ^ (row & 7);
            const ushort* g = W + (size_t)(n0 + row) * KAH + k0 + ss * 8;
            GLD_LDS(g, Bs + chunk * 512);
        }
        __syncthreads();
        #pragma unroll
        for (int kk = 0; kk < 2; ++kk) {
            bf16x8 a[4], bf[2];
            #pragma unroll
            for (int m = 0; m < 4; ++m) {
                int r = wr * 64 + m * 16 + (lane & 15);
                int ss = (kk * 4 + (lane >> 4)) ^ (r & 7);
                a[m] = *(const bf16x8*)&As[r * 64 + ss * 8];
            }
            #pragma unroll
            for (int n = 0; n < 2; ++n) {
                int r = wc * 32 + n * 16 + (lane & 15);
                int ss = (kk * 4 + (lane >> 4)) ^ (r & 7);
                bf[n] = *(const bf16x8*)&Bs[r * 64 + ss * 8];
            }
            #pragma unroll
            for (int m = 0; m < 4; ++m)
                #pragma unroll
                for (int n = 0; n < 2; ++n)
                    acc[m][n] = __builtin_amdgcn_mfma_f32_16x16x32_bf16(a[m], bf[n], acc[m][n], 0, 0, 0);
        }
        __syncthreads();
    }
    ushort* grow = gb + (size_t)z * B * G4P;
    #pragma unroll
    for (int m = 0; m < 4; ++m) {
        #pragma unroll
        for (int n = 0; n < 2; ++n) {
            int c = n0 + wc * 32 + n * 16 + (lane & 15);
            #pragma unroll
            for (int j = 0; j < 4; ++j) {
                int rr = m0 + wr * 64 + m * 16 + (lane >> 4) * 4 + j;
                grow[(size_t)rr * G4P + c] = f2bf(acc[m][n][j]);
            }
        }
    }
}

// ---------------------------------------------------------------------------
// LSTM cell pointwise
__global__ void k_cell(const ushort* __restrict__ gb,
                       const float* __restrict__ b_f, const float* __restrict__ b_b,
                       const float* __restrict__ lentL, const float* __restrict__ lentR,
                       ushort* __restrict__ hb, float* __restrict__ cbuf,
                       ushort* __restrict__ ctxb, int s) {
    int gid = blockIdx.x * blockDim.x + threadIdx.x;
    if (gid >= 4 * B * R) return;
    int r = gid % R;
    int b = (gid / R) % B;
    int z = gid / (B * R);
    int side = z >> 1, dir = z & 1;
    const ushort* g = gb + ((size_t)z * B + b) * G4P;
    const float* bias = dir ? b_b : b_f;
    float gi = bf2f(g[r])         + bias[r];
    float gf = bf2f(g[R + r])     + bias[R + r];
    float gg = bf2f(g[2 * R + r]) + bias[2 * R + r];
    float go = bf2f(g[3 * R + r]) + bias[3 * R + r];
    size_t hoff = ((size_t)z * B + b) * R + r;
    float c_old = cbuf[hoff];
    float si = 1.f / (1.f + __expf(-gi));
    float sf = 1.f / (1.f + __expf(-gf));
    float so = 1.f / (1.f + __expf(-go));
    float c_new = sf * c_old + si * tanhf(gg);
    float h_new = so * tanhf(c_new);
    int len = (int)((side ? lentR : lentL)[b]);
    if (s < len) {
        hb[hoff] = f2bf(h_new);
        cbuf[hoff] = c_new;
        int tpos = dir ? (len - 1 - s) : s;
        ctxb[((size_t)b * CTX2 + side * CTXN + tpos) * CTXS + dir * R + r] = f2bf(h_new);
    }
}

// ---------------------------------------------------------------------------
// scores = att@h2, softmax over 20, weighted ctx sum -> featb[:,300:700]
__global__ __launch_bounds__(256) void k_att2(const float* __restrict__ att,
                                              const float* __restrict__ h2,
                                              const ushort* __restrict__ ctxb,
                                              ushort* __restrict__ featb) {
    int b = blockIdx.x;
    __shared__ float sc[CTX2];
    int tid = threadIdx.x, wave = tid >> 6, lane = tid & 63;
    for (int t = wave; t < CTX2; t += 4) {
        const float* arow = att + ((size_t)b * CTX2 + t) * FMS;
        float v = (lane < HA ? arow[lane] * h2[lane] : 0.f)
                + (lane + 64 < HA ? arow[lane + 64] * h2[lane + 64] : 0.f);
        #pragma unroll
        for (int o = 32; o > 0; o >>= 1) v += __shfl_down(v, o, 64);
        if (lane == 0) sc[t] = v;
    }
    __syncthreads();
    float mx = -1e30f;
    #pragma unroll
    for (int t = 0; t < CTX2; ++t) mx = fmaxf(mx, sc[t]);
    float w[CTX2], sum = 0.f;
    #pragma unroll
    for (int t = 0; t < CTX2; ++t) { w[t] = __expf(sc[t] - mx); sum += w[t]; }
    float inv = 1.f / sum;
    for (int rr = tid; rr < R2; rr += 256) {
        float acc = 0.f;
        #pragma unroll
        for (int t = 0; t < CTX2; ++t)
            acc += w[t] * bf2f(ctxb[((size_t)b * CTX2 + t) * CTXS + rr]);
        featb[(size_t)b * FBS + D + rr] = f2bf(acc * inv);
    }
}

// ---------------------------------------------------------------------------
__device__ __forceinline__ float blk_sum_256(float v, float* red) {
    #pragma unroll
    for (int o = 32; o > 0; o >>= 1) v += __shfl_down(v, o, 64);
    int lane = threadIdx.x & 63, wid = threadIdx.x >> 6;
    if (lane == 0) red[wid] = v;
    __syncthreads();
    float t = red[0] + red[1] + red[2] + red[3];
    __syncthreads();
    return t;
}

__global__ void k_l2norm(float* __restrict__ x, int ncol) {
    int row = blockIdx.x;
    float* p = x + (size_t)row * ncol;
    __shared__ float red[4];
    float ss = 0.f;
    for (int c = threadIdx.x; c < ncol; c += 256) { float v = p[c]; ss += v * v; }
    float tot = blk_sum_256(ss, red);
    float scale = 1.f / sqrtf(fmaxf(tot, 1e-12f));
    for (int c = threadIdx.x; c < ncol; c += 256) p[c] *= scale;
}

__global__ void k_typenorm(const int* __restrict__ type_path,
                           const float* __restrict__ type_tok,
                           float* __restrict__ tnorm) {
    int y = blockIdx.x;
    int c = threadIdx.x;
    __shared__ float red[4];
    float s = 0.f;
    #pragma unroll
    for (int j = 0; j < PL; ++j) {
        int tk = type_path[y * PL + j];
        if (tk >= 0 && tk < NTOK) s += type_tok[(size_t)tk * TD + c];
    }
    float tot = blk_sum_256(s * s, red);
    float scale = 1.f / sqrtf(fmaxf(tot, 1e-12f));
    tnorm[(size_t)y * TD + c] = s * scale;
}

__global__ void k_final(const float* __restrict__ ent,
                        const float* __restrict__ tnorm,
                        float* __restrict__ out) {
    int b = blockIdx.x;
    __shared__ float es[TD];
    for (int c = threadIdx.x; c < TD; c += blockDim.x) es[c] = ent[(size_t)b * TD + c];
    __syncthreads();
    for (int y = threadIdx.x; y < NTY; y += blockDim.x) {
        const float* tn = tnorm + (size_t)y * TD;
        float acc = 0.f;
        #pragma unroll 4
        for (int k = 0; k < TD; ++k) acc += es[k] * tn[k];
        out[(size_t)b * NTY + y] = acc;
    }
}

// ---------------------------------------------------------------------------
static inline char* wsalloc(char*& p, size_t bytes) {
    char* r = p;
    p += (bytes + 255) & ~(size_t)255;
    return r;
}

extern "C" void kernel_launch(void* const* d_in, const int* in_sizes, int n_in,
                              void* d_out, int out_size, void* d_ws, size_t ws_size,
                              hipStream_t stream) {
    const int*   input_data       = (const int*)d_in[0];
    const int*   entMentIndex     = (const int*)d_in[1];
    const int*   entCtxLeftIndex  = (const int*)d_in[2];
    const int*   entCtxRightIndex = (const int*)d_in[3];
    const float* entMentLent      = (const float*)d_in[4];
    const float* ctxLeftLent      = (const float*)d_in[5];
    const float* ctxRightLent     = (const float*)d_in[6];
    const int*   type_path        = (const int*)d_in[7];
    const float* word_embed       = (const float*)d_in[8];
    const float* h_m              = (const float*)d_in[9];
    const float* h1               = (const float*)d_in[10];
    const float* h2               = (const float*)d_in[11];
    const float* Wx_f             = (const float*)d_in[12];
    const float* Wh_f             = (const float*)d_in[13];
    const float* b_f              = (const float*)d_in[14];
    const float* Wx_b             = (const float*)d_in[15];
    const float* Wh_b             = (const float*)d_in[16];
    const float* b_b              = (const float*)d_in[17];
    const float* dense_W          = (const float*)d_in[18];
    const float* dense_b          = (const float*)d_in[19];
    const float* type_tok         = (const float*)d_in[20];
    float* out = (float*)d_out;

    char* p = (char*)d_ws;
    ushort* xLb   = (ushort*)wsalloc(p, (size_t)B * CTXN * XS * 2);
    ushort* xRb   = (ushort*)wsalloc(p, (size_t)B * CTXN * XS * 2);
    ushort* hb    = (ushort*)wsalloc(p, (size_t)4 * B * R * 2);
    float*  cbuf  = (float*) wsalloc(p, (size_t)4 * B * R * 4);
    ushort* gb    = (ushort*)wsalloc(p, (size_t)4 * B * G4P * 2);
    ushort* ctxb  = (ushort*)wsalloc(p, (size_t)B * CTX2 * CTXS * 2);
    float*  att   = (float*) wsalloc(p, (size_t)B * CTX2 * FMS * 4);
    ushort* featb = (ushort*)wsalloc(p, (size_t)B * FBS * 2);
    ushort* f1b   = (ushort*)wsalloc(p, (size_t)B * F1S * 2);
    float*  fm    = (float*) wsalloc(p, (size_t)B * FMS * 4);
    float*  ent   = (float*) wsalloc(p, (size_t)B * TD * 4);
    float*  tnorm = (float*) wsalloc(p, (size_t)NTY * TD * 4);
    ushort* Wt    = (ushort*)wsalloc(p, (size_t)2 * G4P * KAH * 2);
    ushort* h1t   = (ushort*)wsalloc(p, (size_t)FMS * CTXS * 2);
    ushort* h_mt  = (ushort*)wsalloc(p, (size_t)FMS * F1S * 2);
    ushort* dWt   = (ushort*)wsalloc(p, (size_t)TD * FBS * 2);
    ushort* zbuf  = (ushort*)wsalloc(p, 256);

    // zero-init state and masked/padded buffers
    hipMemsetAsync(hb,   0, (size_t)4 * B * R * 2, stream);
    hipMemsetAsync(cbuf, 0, (size_t)4 * B * R * 4, stream);
    hipMemsetAsync(ctxb, 0, (size_t)B * CTX2 * CTXS * 2, stream);
    hipMemsetAsync(featb,0, (size_t)B * FBS * 2, stream);
    hipMemsetAsync(f1b,  0, (size_t)B * F1S * 2, stream);
    hipMemsetAsync(zbuf, 0, 256, stream);

    // weight prep
    k_prepw<<<(2 * G4P * KAH + 255) / 256, 256, 0, stream>>>(Wx_f, Wh_f, Wx_b, Wh_b, Wt);
    k_preph1<<<(FMS * CTXS + 255) / 256, 256, 0, stream>>>(h1, h1t);
    k_prephm<<<(FMS * F1S + 255) / 256, 256, 0, stream>>>(h_m, h_mt);
    k_prepdw<<<(TD * FBS + 255) / 256, 256, 0, stream>>>(dense_W, dWt);

    // gathers + f1
    k_gatherb<<<(2 * B * CTXN + 3) / 4, 256, 0, stream>>>(entCtxLeftIndex, entCtxRightIndex,
                                                          input_data, word_embed, xLb, xRb);
    k_f1<<<B, 256, 0, stream>>>(entMentIndex, entMentLent, input_data, word_embed, featb, f1b);

    // fm = f1 @ h_m  (M=4096, N=128, K=320)
    k_mfma<3><<<dim3(FMS / 64, B / 128), 256, 0, stream>>>(f1b, F1S, h_mt, F1S, fm, FMS, F1S, nullptr);

    // 10 recurrent steps
    for (int s = 0; s < CTXN; ++s) {
        dim3 gg(G4P / 64, B / 128, 4);
        k_gates_mfma<<<gg, 256, 0, stream>>>(xLb, xRb, hb, Wt, ctxLeftLent, ctxRightLent,
                                             zbuf, gb, s);
        int nthr = 4 * B * R;
        k_cell<<<(nthr + 255) / 256, 256, 0, stream>>>(gb, b_f, b_b, ctxLeftLent, ctxRightLent,
                                                       hb, cbuf, ctxb, s);
    }

    // att = relu(ctx @ h1 + fm)  (M=81920, N=128, K=448)
    k_mfma<2><<<dim3(FMS / 64, (B * CTX2) / 128), 256, 0, stream>>>(ctxb, CTXS, h1t, CTXS,
                                                                    att, FMS, CTXS, fm);
    // softmax + weighted sum -> featb[:,300:700]
    k_att2<<<B, 256, 0, stream>>>(att, h2, ctxb, featb);

    // ent = relu(feat @ dense_W + b)  (M=4096, N=256, K=704)
    k_mfma<1><<<dim3(TD / 64, B / 128), 256, 0, stream>>>(featb, FBS, dWt, FBS,
                                                          ent, TD, FBS, dense_b);
    k_l2norm<<<B, 256, 0, stream>>>(ent, TD);
    k_typenorm<<<NTY, TD, 0, stream>>>(type_path, type_tok, tnorm);
    k_final<<<B, 128, 0, stream>>>(ent, tnorm, out);
}